// Round 3
// baseline (622.983 us; speedup 1.0000x reference)
//
#include <hip/hip_runtime.h>
#include <hip/hip_bf16.h>

#define H 4096
#define NEXP 256
#define BM 32
#define BK 32
#define TOPK 8
#define NGROUP 8
#define TOPKG 4
#define ROUTED_SCALING 2.5f

// LDS (static, 54272 B -> 2 blocks/CU):
//   GEMM:  Ws[32][388] floats @ 0       col(e) = 12*(e>>3) + (e&7)   [k][e-swizzled]
//          Xs[32][36]  floats @ 12416   [k][token] (b128 a-read broadcasts)
//   Gate:  SC[256][32] floats @ 0       (aliases Ws; col swizzled t^(e>>3))
#define WS_STRIDE 388
#define XS_STRIDE 36
#define WS_FLOATS (BK * WS_STRIDE)
#define SMEM_FLOATS (WS_FLOATS + BK * XS_STRIDE)   // 13568 floats = 54272 B

__global__ __launch_bounds__(256, 2) void moe_gate_f32(
    const float* __restrict__ X, const float* __restrict__ W,
    const float* __restrict__ bias, float* __restrict__ out, int T)
{
    __shared__ float smem[SMEM_FLOATS];
    float* Ws = smem;
    float* Xs = smem + WS_FLOATS;
    float* SC = smem;                 // gate-phase alias

    const int tid = threadIdx.x;
    const int tq  = tid >> 5;         // 0..7 : token quad (tokens 4tq..4tq+3)
    const int tx  = tid & 31;         // 0..31: expert octet (experts 8tx..8tx+7)
    const int m0  = blockIdx.x * BM;

    // staging mapping
    const int q  = tid & 7;           // k-quad within BK
    const int sx = tid >> 3;          // 0..31: X token row / W expert row base

    float acc[4][8];
#pragma unroll
    for (int r = 0; r < 4; ++r)
#pragma unroll
        for (int c = 0; c < 8; ++c) acc[r][c] = 0.f;

    float4 xr, wr[8];
    const float* Xbase = X + (size_t)(m0 + sx) * H + 4 * q;
    const float* Wbase = W + (size_t)sx * H + 4 * q;

    auto loadTile = [&](int k0) {
        xr = *(const float4*)(Xbase + k0);
#pragma unroll
        for (int i = 0; i < 8; ++i)
            wr[i] = *(const float4*)(Wbase + (size_t)(32 * i) * H + k0);
    };
    auto storeTile = [&]() {
        // X tile transposed: Xs[k][t]
        Xs[(4 * q + 0) * XS_STRIDE + sx] = xr.x;
        Xs[(4 * q + 1) * XS_STRIDE + sx] = xr.y;
        Xs[(4 * q + 2) * XS_STRIDE + sx] = xr.z;
        Xs[(4 * q + 3) * XS_STRIDE + sx] = xr.w;
#pragma unroll
        for (int i = 0; i < 8; ++i) {
            const int e = sx + 32 * i;
            const int col = 12 * (e >> 3) + (e & 7);
            Ws[(4 * q + 0) * WS_STRIDE + col] = wr[i].x;
            Ws[(4 * q + 1) * WS_STRIDE + col] = wr[i].y;
            Ws[(4 * q + 2) * WS_STRIDE + col] = wr[i].z;
            Ws[(4 * q + 3) * WS_STRIDE + col] = wr[i].w;
        }
    };

    loadTile(0);
    for (int k0 = 0; k0 < H; k0 += BK) {
        storeTile();
        __syncthreads();
        if (k0 + BK < H) loadTile(k0 + BK);
#pragma unroll 8
        for (int kk = 0; kk < BK; ++kk) {
            float a[4], b[8];
            *(float4*)&a[0] = *(const float4*)&Xs[kk * XS_STRIDE + 4 * tq];
            *(float4*)&b[0] = *(const float4*)&Ws[kk * WS_STRIDE + 12 * tx];
            *(float4*)&b[4] = *(const float4*)&Ws[kk * WS_STRIDE + 12 * tx + 4];
#pragma unroll
            for (int r = 0; r < 4; ++r)
#pragma unroll
                for (int c = 0; c < 8; ++c)
                    acc[r][c] = fmaf(a[r], b[c], acc[r][c]);
        }
        __syncthreads();
    }

    // epilogue: SC[e][t ^ (e>>3)] = sigmoid(logit) + bias
#pragma unroll
    for (int c = 0; c < 8; ++c) {
        const int e = 8 * tx + c;
        const float be = bias[e];
#pragma unroll
        for (int r = 0; r < 4; ++r) {
            const int t = 4 * tq + r;
            const float s = 1.0f / (1.0f + expf(-acc[r][c]));
            SC[e * 32 + (t ^ tx)] = s + be;   // e>>3 == tx
        }
    }
    __syncthreads();

    if (tid < BM) {
        const int t = tid;
        // 1) per-group top-2 sums
        float gs[NGROUP];
#pragma unroll
        for (int g = 0; g < NGROUP; ++g) {
            float m1 = -1e30f, m2 = -1e30f;
            for (int j = 0; j < 32; ++j) {
                const int e = g * 32 + j;
                const float v = SC[e * 32 + (t ^ (e >> 3))];
                if (v > m1) { m2 = m1; m1 = v; }
                else if (v > m2) { m2 = v; }
            }
            gs[g] = m1 + m2;
        }
        // 2) top-4 groups (strict >, ascending scan -> lower index on ties)
        unsigned gmask = 0;
        for (int r = 0; r < TOPKG; ++r) {
            int bi = 0; float bv = -1e30f;
#pragma unroll
            for (int g = 0; g < NGROUP; ++g) {
                if (!((gmask >> g) & 1u) && gs[g] > bv) { bv = gs[g]; bi = g; }
            }
            gmask |= (1u << bi);
        }
        int glist[TOPKG], ng = 0;
#pragma unroll
        for (int g = 0; g < NGROUP; ++g)
            if ((gmask >> g) & 1u) glist[ng++] = g;
        // 3) top-8 experts within allowed groups
        int eidx[TOPK]; float sval[TOPK];
        unsigned cmask[TOPKG] = {0u, 0u, 0u, 0u};
        float wsum = 0.f;
        for (int r = 0; r < TOPK; ++r) {
            float bv = -1e30f; int bgi = 0, bj = 0;
            for (int gi = 0; gi < TOPKG; ++gi) {
                const int g = glist[gi];
                for (int j = 0; j < 32; ++j) {
                    if ((cmask[gi] >> j) & 1u) continue;
                    const int e = g * 32 + j;
                    const float v = SC[e * 32 + (t ^ (e >> 3))];
                    if (v > bv) { bv = v; bgi = gi; bj = j; }
                }
            }
            cmask[bgi] |= (1u << bj);
            const int e = glist[bgi] * 32 + bj;
            eidx[r] = e;
            const float sig = bv - bias[e];
            sval[r] = sig;
            wsum += sig;
        }
        const float scale = ROUTED_SCALING / (wsum + 1e-20f);
        const size_t gt = (size_t)(m0 + t);
#pragma unroll
        for (int r = 0; r < TOPK; ++r) {
            out[gt * TOPK + r] = (float)eidx[r];
            out[(size_t)T * TOPK + gt * TOPK + r] = sval[r] * scale;
        }
    }
}

extern "C" void kernel_launch(void* const* d_in, const int* in_sizes, int n_in,
                              void* d_out, int out_size, void* d_ws, size_t ws_size,
                              hipStream_t stream) {
    const float* X = (const float*)d_in[0];
    const float* W = (const float*)d_in[1];
    const float* B = (const float*)d_in[2];
    float* out = (float*)d_out;
    const int T = in_sizes[0] / H;            // 16384
    dim3 grid(T / BM), block(256);
    moe_gate_f32<<<grid, block, 0, stream>>>(X, W, B, out, T);
}

// Round 5
// 422.104 us; speedup vs baseline: 1.4759x; 1.4759x over previous
//
#include <hip/hip_runtime.h>
#include <hip/hip_bf16.h>

#define H 4096
#define NEXP 256
#define TOPK 8
#define NGROUP 8
#define TOPKG 4
#define ROUTED_SCALING 2.5f

typedef __attribute__((ext_vector_type(8)))  short  s16x8;
typedef __attribute__((ext_vector_type(16))) float  f32x16;

// ============================================================================
// Pre-kernel: split W [256][4096] fp32 into 3 exact bf16 levels (truncation;
// w1+w2+w3 == w bit-exactly), stored in mfma_f32_32x32x16_bf16 B-fragment
// order: frag addr = v*2097152 + ((etile*256 + ks)*64 + lane)*16;
// lane l holds W[etile*32 + (l&31)][16*ks + 8*(l>>5) + j], j=0..7.
// ============================================================================
__global__ __launch_bounds__(256) void wsplit_kernel(
    const float* __restrict__ W, char* __restrict__ ws)
{
    const int t  = blockIdx.x * 256 + threadIdx.x;   // 0..131071
    const int l  = t & 63;
    const int ks = (t >> 6) & 255;
    const int eg = t >> 14;                          // expert tile 0..7
    const int expert = eg * 32 + (l & 31);
    const int k0 = ks * 16 + (l >> 5) * 8;
    const float* src = W + (size_t)expert * H + k0;
    float xf[8];
    *(float4*)&xf[0] = *(const float4*)(src);
    *(float4*)&xf[4] = *(const float4*)(src + 4);
    union { unsigned short u[8]; int4 q; } o1, o2, o3;
#pragma unroll
    for (int j = 0; j < 8; ++j) {
        const float x = xf[j];
        const unsigned b = __float_as_uint(x);
        o1.u[j] = (unsigned short)(b >> 16);
        const float r1 = x - __uint_as_float(b & 0xFFFF0000u);
        const unsigned b2 = __float_as_uint(r1);
        o2.u[j] = (unsigned short)(b2 >> 16);
        const float r2 = r1 - __uint_as_float(b2 & 0xFFFF0000u);
        o3.u[j] = (unsigned short)(__float_as_uint(r2) >> 16);
    }
    const size_t off = ((size_t)((eg * 256 + ks) * 64 + l)) * 16;
    *(int4*)(ws + off)           = o1.q;
    *(int4*)(ws + 2097152 + off) = o2.q;
    *(int4*)(ws + 4194304 + off) = o3.q;
}

// ============================================================================
// Main kernel: 256 blocks x 512 threads. Block = 64 tokens x 256 experts.
// Wave = 32 tok x 64 exp. K-loop: no LDS/barriers. A: global fp32 -> exact
// 3-level bf16 split in registers (4-deep prefetch). B: frag bf16 (2-deep).
// NUMERICS: P11 (x1*w1) goes to acc_hi, drained to fp64 every 4 K-steps
// (C=0 chunking -> no large-magnitude fp32 roundings). The 5 small cross
// products chain in acc_rest (2^-8 scale -> noise negligible).
// ============================================================================
__global__ __launch_bounds__(512, 2) void moe_mfma_kernel(
    const float* __restrict__ X, const char* __restrict__ ws,
    const float* __restrict__ bias, float* __restrict__ out, int T)
{
    __shared__ float SC[NEXP * 32];   // 32 KB, epilogue only
    const int tid = threadIdx.x;
    const int l   = tid & 63;
    const int wid = tid >> 6;        // 0..7
    const int tg  = wid & 1;         // token group
    const int eg  = wid >> 1;        // expert group 0..3
    const int m0  = blockIdx.x * 64;

    const float* Xp = X + (size_t)(m0 + 32 * tg + (l & 31)) * H + 8 * (l >> 5);
    const char* bp0 = ws + (size_t)(2 * eg)     * 262144 + (size_t)l * 16;
    const char* bp1 = ws + (size_t)(2 * eg + 1) * 262144 + (size_t)l * 16;

    f32x16 acc_hi[2], acc_rest[2];
    double tot[2][16];
#pragma unroll
    for (int et = 0; et < 2; ++et) {
#pragma unroll
        for (int r = 0; r < 16; ++r) {
            acc_hi[et][r] = 0.f; acc_rest[et][r] = 0.f; tot[et][r] = 0.0;
        }
    }

    float ra[4][8];                  // A fp32, 4-deep
    union BF { int4 q; s16x8 v; };
    BF rb[2][6];                     // B frags, 2-deep; idx = 2*v + et
    union AF { s16x8 v; unsigned short u[8]; };

#define LOADA(ks, sa)                                                     \
    { *(float4*)&ra[sa][0] = *(const float4*)(Xp + 16 * (ks));            \
      *(float4*)&ra[sa][4] = *(const float4*)(Xp + 16 * (ks) + 4); }
#define LOADB(ks, sb)                                                     \
    { _Pragma("unroll")                                                   \
      for (int v = 0; v < 3; ++v) {                                       \
        rb[sb][2*v+0].q = *(const int4*)(bp0 + v * 2097152 + (ks) * 1024);\
        rb[sb][2*v+1].q = *(const int4*)(bp1 + v * 2097152 + (ks) * 1024);\
      } }

    LOADA(0, 0) LOADA(1, 1) LOADA(2, 2) LOADA(3, 3)
    LOADB(0, 0) LOADB(1, 1)

#define STEP(ks, sa, sb)                                                  \
    {   AF af[3];                                                         \
        _Pragma("unroll")                                                 \
        for (int j = 0; j < 8; ++j) {                                     \
            const float x = ra[sa][j];                                    \
            const unsigned b = __float_as_uint(x);                        \
            af[0].u[j] = (unsigned short)(b >> 16);                       \
            const float r1 = x - __uint_as_float(b & 0xFFFF0000u);        \
            const unsigned b2 = __float_as_uint(r1);                      \
            af[1].u[j] = (unsigned short)(b2 >> 16);                      \
            const float r2 = r1 - __uint_as_float(b2 & 0xFFFF0000u);      \
            af[2].u[j] = (unsigned short)(__float_as_uint(r2) >> 16);     \
        }                                                                 \
        _Pragma("unroll")                                                 \
        for (int et = 0; et < 2; ++et) {                                  \
            acc_hi[et] = __builtin_amdgcn_mfma_f32_32x32x16_bf16(         \
                af[0].v, rb[sb][et].v, acc_hi[et], 0, 0, 0);              \
            acc_rest[et] = __builtin_amdgcn_mfma_f32_32x32x16_bf16(       \
                af[0].v, rb[sb][2 + et].v, acc_rest[et], 0, 0, 0);        \
            acc_rest[et] = __builtin_amdgcn_mfma_f32_32x32x16_bf16(       \
                af[1].v, rb[sb][et].v, acc_rest[et], 0, 0, 0);            \
            acc_rest[et] = __builtin_amdgcn_mfma_f32_32x32x16_bf16(       \
                af[1].v, rb[sb][2 + et].v, acc_rest[et], 0, 0, 0);        \
            acc_rest[et] = __builtin_amdgcn_mfma_f32_32x32x16_bf16(       \
                af[0].v, rb[sb][4 + et].v, acc_rest[et], 0, 0, 0);        \
            acc_rest[et] = __builtin_amdgcn_mfma_f32_32x32x16_bf16(       \
                af[2].v, rb[sb][et].v, acc_rest[et], 0, 0, 0);            \
        }                                                                 \
        if ((ks) + 4 < 256) LOADA((ks) + 4, sa)                           \
        if ((ks) + 2 < 256) LOADB((ks) + 2, sb)                           \
    }

    for (int k4 = 0; k4 < 256; k4 += 4) {
        STEP(k4 + 0, 0, 0)
        STEP(k4 + 1, 1, 1)
        STEP(k4 + 2, 2, 0)
        STEP(k4 + 3, 3, 1)
        // drain chunk (K=64) into fp64 totals; reset chunk accumulator
#pragma unroll
        for (int et = 0; et < 2; ++et) {
#pragma unroll
            for (int r = 0; r < 16; ++r) {
                tot[et][r] += (double)acc_hi[et][r];
                acc_hi[et][r] = 0.f;
            }
        }
    }
#undef STEP
#undef LOADA
#undef LOADB

    // ---- epilogue: two 32-token phases ----
    for (int ph = 0; ph < 2; ++ph) {
        if (tg == ph) {
#pragma unroll
            for (int et = 0; et < 2; ++et) {
                const int e = 64 * eg + 32 * et + (l & 31);
                const float be = bias[e];
#pragma unroll
                for (int r = 0; r < 16; ++r) {
                    const int ti = (r & 3) + 8 * (r >> 2) + 4 * (l >> 5);
                    const float logit =
                        (float)(tot[et][r] + (double)acc_rest[et][r]);
                    const float s = 1.0f / (1.0f + expf(-logit));
                    SC[e * 32 + (ti ^ (e & 31))] = s + be;
                }
            }
        }
        __syncthreads();
        if (tid < 32) {
            const int t = tid;
            float gs[NGROUP];
#pragma unroll
            for (int g = 0; g < NGROUP; ++g) {
                float m1 = -1e30f, m2 = -1e30f;
                for (int j = 0; j < 32; ++j) {
                    const int e = g * 32 + j;
                    const float v = SC[e * 32 + (t ^ (e & 31))];
                    if (v > m1) { m2 = m1; m1 = v; }
                    else if (v > m2) { m2 = v; }
                }
                gs[g] = m1 + m2;
            }
            unsigned gmask = 0;
            for (int r = 0; r < TOPKG; ++r) {
                int bi = 0; float bv = -1e30f;
#pragma unroll
                for (int g = 0; g < NGROUP; ++g)
                    if (!((gmask >> g) & 1u) && gs[g] > bv) { bv = gs[g]; bi = g; }
                gmask |= (1u << bi);
            }
            int glist[TOPKG], ng = 0;
#pragma unroll
            for (int g = 0; g < NGROUP; ++g)
                if ((gmask >> g) & 1u) glist[ng++] = g;
            int eidx[TOPK]; float sval[TOPK];
            unsigned cmask[TOPKG] = {0u, 0u, 0u, 0u};
            float wsum = 0.f;
            for (int r = 0; r < TOPK; ++r) {
                float bv = -1e30f; int bgi = 0, bj = 0;
                for (int gi = 0; gi < TOPKG; ++gi) {
                    const int g = glist[gi];
                    for (int j = 0; j < 32; ++j) {
                        if ((cmask[gi] >> j) & 1u) continue;
                        const int e = g * 32 + j;
                        const float v = SC[e * 32 + (t ^ (e & 31))];
                        if (v > bv) { bv = v; bgi = gi; bj = j; }
                    }
                }
                cmask[bgi] |= (1u << bj);
                const int e = glist[bgi] * 32 + bj;
                eidx[r] = e;
                const float sig = bv - bias[e];
                sval[r] = sig; wsum += sig;
            }
            const float scale = ROUTED_SCALING / (wsum + 1e-20f);
            const size_t gt = (size_t)(m0 + 32 * ph + t);
#pragma unroll
            for (int r = 0; r < TOPK; ++r) {
                out[gt * TOPK + r] = (float)eidx[r];
                out[(size_t)T * TOPK + gt * TOPK + r] = sval[r] * scale;
            }
        }
        __syncthreads();
    }
}

// ============================================================================
// Fallback (verified round-3 fp32 kernel) if ws is too small for the split-W.
// ============================================================================
#define BMF 32
#define BKF 32
#define WS_STRIDE 388
#define XS_STRIDE 36
#define WS_FLOATS (BKF * WS_STRIDE)
#define SMEM_FLOATS (WS_FLOATS + BKF * XS_STRIDE)

__global__ __launch_bounds__(256, 2) void moe_gate_f32(
    const float* __restrict__ X, const float* __restrict__ W,
    const float* __restrict__ bias, float* __restrict__ out, int T)
{
    __shared__ float smem[SMEM_FLOATS];
    float* Ws = smem;
    float* Xs = smem + WS_FLOATS;
    float* SC = smem;
    const int tid = threadIdx.x;
    const int tq  = tid >> 5;
    const int tx  = tid & 31;
    const int m0  = blockIdx.x * BMF;
    const int q  = tid & 7;
    const int sx = tid >> 3;
    float acc[4][8];
#pragma unroll
    for (int r = 0; r < 4; ++r)
#pragma unroll
        for (int c = 0; c < 8; ++c) acc[r][c] = 0.f;
    float4 xr, wr[8];
    const float* Xbase = X + (size_t)(m0 + sx) * H + 4 * q;
    const float* Wbase = W + (size_t)sx * H + 4 * q;
    auto loadTile = [&](int k0) {
        xr = *(const float4*)(Xbase + k0);
#pragma unroll
        for (int i = 0; i < 8; ++i)
            wr[i] = *(const float4*)(Wbase + (size_t)(32 * i) * H + k0);
    };
    auto storeTile = [&]() {
        Xs[(4 * q + 0) * XS_STRIDE + sx] = xr.x;
        Xs[(4 * q + 1) * XS_STRIDE + sx] = xr.y;
        Xs[(4 * q + 2) * XS_STRIDE + sx] = xr.z;
        Xs[(4 * q + 3) * XS_STRIDE + sx] = xr.w;
#pragma unroll
        for (int i = 0; i < 8; ++i) {
            const int e = sx + 32 * i;
            const int col = 12 * (e >> 3) + (e & 7);
            Ws[(4 * q + 0) * WS_STRIDE + col] = wr[i].x;
            Ws[(4 * q + 1) * WS_STRIDE + col] = wr[i].y;
            Ws[(4 * q + 2) * WS_STRIDE + col] = wr[i].z;
            Ws[(4 * q + 3) * WS_STRIDE + col] = wr[i].w;
        }
    };
    loadTile(0);
    for (int k0 = 0; k0 < H; k0 += BKF) {
        storeTile();
        __syncthreads();
        if (k0 + BKF < H) loadTile(k0 + BKF);
#pragma unroll 8
        for (int kk = 0; kk < BKF; ++kk) {
            float a[4], b[8];
            *(float4*)&a[0] = *(const float4*)&Xs[kk * XS_STRIDE + 4 * tq];
            *(float4*)&b[0] = *(const float4*)&Ws[kk * WS_STRIDE + 12 * tx];
            *(float4*)&b[4] = *(const float4*)&Ws[kk * WS_STRIDE + 12 * tx + 4];
#pragma unroll
            for (int r = 0; r < 4; ++r)
#pragma unroll
                for (int c = 0; c < 8; ++c)
                    acc[r][c] = fmaf(a[r], b[c], acc[r][c]);
        }
        __syncthreads();
    }
#pragma unroll
    for (int c = 0; c < 8; ++c) {
        const int e = 8 * tx + c;
        const float be = bias[e];
#pragma unroll
        for (int r = 0; r < 4; ++r) {
            const int t = 4 * tq + r;
            const float s = 1.0f / (1.0f + expf(-acc[r][c]));
            SC[e * 32 + (t ^ tx)] = s + be;
        }
    }
    __syncthreads();
    if (tid < BMF) {
        const int t = tid;
        float gs[NGROUP];
#pragma unroll
        for (int g = 0; g < NGROUP; ++g) {
            float m1 = -1e30f, m2 = -1e30f;
            for (int j = 0; j < 32; ++j) {
                const int e = g * 32 + j;
                const float v = SC[e * 32 + (t ^ (e >> 3))];
                if (v > m1) { m2 = m1; m1 = v; }
                else if (v > m2) { m2 = v; }
            }
            gs[g] = m1 + m2;
        }
        unsigned gmask = 0;
        for (int r = 0; r < TOPKG; ++r) {
            int bi = 0; float bv = -1e30f;
#pragma unroll
            for (int g = 0; g < NGROUP; ++g)
                if (!((gmask >> g) & 1u) && gs[g] > bv) { bv = gs[g]; bi = g; }
            gmask |= (1u << bi);
        }
        int glist[TOPKG], ng = 0;
#pragma unroll
        for (int g = 0; g < NGROUP; ++g)
            if ((gmask >> g) & 1u) glist[ng++] = g;
        int eidx[TOPK]; float sval[TOPK];
        unsigned cmask[TOPKG] = {0u, 0u, 0u, 0u};
        float wsum = 0.f;
        for (int r = 0; r < TOPK; ++r) {
            float bv = -1e30f; int bgi = 0, bj = 0;
            for (int gi = 0; gi < TOPKG; ++gi) {
                const int g = glist[gi];
                for (int j = 0; j < 32; ++j) {
                    if ((cmask[gi] >> j) & 1u) continue;
                    const int e = g * 32 + j;
                    const float v = SC[e * 32 + (t ^ (e >> 3))];
                    if (v > bv) { bv = v; bgi = gi; bj = j; }
                }
            }
            cmask[bgi] |= (1u << bj);
            const int e = glist[bgi] * 32 + bj;
            eidx[r] = e;
            const float sig = bv - bias[e];
            sval[r] = sig; wsum += sig;
        }
        const float scale = ROUTED_SCALING / (wsum + 1e-20f);
        const size_t gt = (size_t)(m0 + t);
#pragma unroll
        for (int r = 0; r < TOPK; ++r) {
            out[gt * TOPK + r] = (float)eidx[r];
            out[(size_t)T * TOPK + gt * TOPK + r] = sval[r] * scale;
        }
    }
}

extern "C" void kernel_launch(void* const* d_in, const int* in_sizes, int n_in,
                              void* d_out, int out_size, void* d_ws, size_t ws_size,
                              hipStream_t stream) {
    const float* X = (const float*)d_in[0];
    const float* W = (const float*)d_in[1];
    const float* B = (const float*)d_in[2];
    float* out = (float*)d_out;
    const int T = in_sizes[0] / H;            // 16384
    if (ws_size >= (size_t)6 * 1024 * 1024) {
        wsplit_kernel<<<512, 256, 0, stream>>>(W, (char*)d_ws);
        moe_mfma_kernel<<<T / 64, 512, 0, stream>>>(X, (const char*)d_ws, B, out, T);
    } else {
        moe_gate_f32<<<T / 32, 256, 0, stream>>>(X, W, B, out, T);
    }
}